// Round 2
// baseline (881.249 us; speedup 1.0000x reference)
//
#include <hip/hip_runtime.h>
#include <math.h>

#define HW_PIX 65536
#define H_BEV 256
#define W_BEV 256
#define C_FEAT 128
#define F_FRAMES 4
#define N_AGENTS 5
#define CSPLIT 4
#define CCHUNK (C_FEAT / CSPLIT)   // 32 channels per block
#define NPAIR 4                    // 4 float2 pairs per thread, 512-px apart

struct dd2 { double x, y; };

__device__ __forceinline__ void fma2(dd2& a, const float2 u, const float2 v) {
    a.x += (double)u.x * (double)v.x;
    a.y += (double)u.y * (double)v.y;
}
__device__ __forceinline__ void fma2s(dd2& a, const double w, const float2 v) {
    a.x += w * (double)v.x;
    a.y += w * (double)v.y;
}

// softmax(0.5^i, i=0..3) in double
__device__ __forceinline__ double hist_weight(int i) {
    const double e0 = exp(1.0), e1 = exp(0.5), e2 = exp(0.25), e3 = exp(0.125);
    const double s = e0 + e1 + e2 + e3;
    double v = (i == 0) ? e0 : (i == 1) ? e1 : (i == 2) ? e2 : e3;
    return v / s;
}

// Kernel 1: uniform-work dot kernel.
// Block = (frame, channel-quarter); 256 threads; each thread owns 4 float2
// pairs at px = blk*2048 + j*512 + 2*tid (j=0..3).
//
// Rationale (round-1 theory): all channel/agent streams sit at power-of-two
// strides (256 KB, 32 MB), so a wave's in-flight loads previously aliased to
// ONE L2-set group / DRAM row-group -> per-set MSHR serialization at ~1.3 TB/s.
// Spreading each thread's pixels 2 KB apart makes the in-flight window span
// 4 set groups (addr bit 11 varies), and the block now covers a contiguous
// 2048-px range -> 8 KB sequential DRAM runs per plane (vs 2 KB).
// Per-pixel accumulation order is IDENTICAL to the verified kernel
// (sequential c within split) -> bit-identical part, absmax stays 0.
// Partials layout: part[fs=frame*4+split][dot(5)][HW_PIX] as double.
__global__ __launch_bounds__(256) void dot_kernel(
        const float* __restrict__ hist, const float* __restrict__ mlp_w,
        double* __restrict__ part) {
    const int fs = blockIdx.y;            // 0..15
    const int frame = fs >> 2;
    const int split = fs & 3;
    const int c0 = split * CCHUNK;
    const int pbase = blockIdx.x * (NPAIR * 512) + (threadIdx.x << 1);

    const float* base = hist + (size_t)frame * N_AGENTS * C_FEAT * HW_PIX
                             + (size_t)c0 * HW_PIX + pbase;
    const float* a0 = base;                                   // ego (agent 0)
    const float* a1 = base + (size_t)1 * C_FEAT * HW_PIX;     // agent 1
    const float* a2 = base + (size_t)2 * C_FEAT * HW_PIX;     // agent 2
    const float* a4 = base + (size_t)4 * C_FEAT * HW_PIX;     // agent 4

    dd2 d1[NPAIR], d2_[NPAIR], q1[NPAIR], q2[NPAIR], q4[NPAIR];
    #pragma unroll
    for (int j = 0; j < NPAIR; ++j) {
        d1[j] = {0, 0}; d2_[j] = {0, 0};
        q1[j] = {0, 0}; q2[j] = {0, 0}; q4[j] = {0, 0};
    }

    #pragma unroll 2
    for (int c = 0; c < CCHUNK; ++c) {
        const double wc = (double)mlp_w[c0 + c];   // uniform -> scalar
        const size_t co = (size_t)c * HW_PIX;
        #pragma unroll
        for (int j = 0; j < NPAIR; ++j) {
            const int o = j * 512;
            const float2 e  = *(const float2*)(a0 + co + o);
            const float2 n1 = *(const float2*)(a1 + co + o);
            const float2 n2 = *(const float2*)(a2 + co + o);
            const float2 n4 = *(const float2*)(a4 + co + o);
            fma2(d1[j], e, n1);
            fma2(d2_[j], e, n2);
            fma2s(q1[j], wc, n1);
            fma2s(q2[j], wc, n2);
            fma2s(q4[j], wc, n4);
        }
    }

    double* pb = part + ((size_t)fs * 5) * HW_PIX + pbase;
    #pragma unroll
    for (int j = 0; j < NPAIR; ++j) {
        const int o = j * 512;
        *(double2*)(pb + 0 * HW_PIX + o) = make_double2(d1[j].x, d1[j].y);
        *(double2*)(pb + 1 * HW_PIX + o) = make_double2(d2_[j].x, d2_[j].y);
        *(double2*)(pb + 2 * HW_PIX + o) = make_double2(q1[j].x, q1[j].y);
        *(double2*)(pb + 3 * HW_PIX + o) = make_double2(q2[j].x, q2[j].y);
        *(double2*)(pb + 4 * HW_PIX + o) = make_double2(q4[j].x, q4[j].y);
    }
}

// Kernel 2: per pixel, reduce the 4 channel-splits per frame, softmax over
// {d1,d2} -> ctx.w, sigmoid, history-weight sum over frames, threshold.
__global__ __launch_bounds__(256) void mask_kernel(
        const double* __restrict__ part, const float* __restrict__ mlp_b,
        float* __restrict__ mask) {
    const int p = blockIdx.x * blockDim.x + threadIdx.x;
    if (p >= HW_PIX) return;
    const double bias = (double)mlp_b[0];
    const double scale = 0.08838834764831844506;  // 1/sqrt(128)
    double acc0 = 0.0, acc1 = 0.0;
    #pragma unroll
    for (int f = 0; f < F_FRAMES; ++f) {
        double d1 = 0, d2 = 0, q1 = 0, q2 = 0, q4 = 0;
        #pragma unroll
        for (int s = 0; s < CSPLIT; ++s) {
            const double* pp = part + ((size_t)(f * CSPLIT + s) * 5) * HW_PIX + p;
            d1 += pp[0 * HW_PIX];
            d2 += pp[1 * HW_PIX];
            q1 += pp[2 * HW_PIX];
            q2 += pp[3 * HW_PIX];
            q4 += pp[4 * HW_PIX];
        }
        double x1 = d1 * scale, x2 = d2 * scale;
        double m = fmax(x1, x2);
        double e1 = exp(x1 - m), e2 = exp(x2 - m);
        double ctxw = (e1 * q1 + e2 * q2) / (e1 + e2) + bias;
        double s0 = 1.0 / (1.0 + exp(-ctxw));        // chunk0 neighbor score
        double s1 = 1.0 / (1.0 + exp(-(q4 + bias))); // chunk1 neighbor score
        double hwf = hist_weight(f);
        acc0 += hwf * s0;
        acc1 += hwf * s1;
    }
    mask[p]          = (acc0 > 0.5) ? 1.0f : 0.0f;
    mask[HW_PIX + p] = (acc1 > 0.5) ? 1.0f : 0.0f;
}

// Kernel 3: 3x3 clamped max-pool on {0,1} masks; egos (agents 0,3) are 1.0.
__global__ __launch_bounds__(256) void pool_kernel(
        const float* __restrict__ mask, float* __restrict__ out) {
    const int p = blockIdx.x * blockDim.x + threadIdx.x;
    if (p >= HW_PIX) return;
    const int y = p >> 8, x = p & 255;
    float m[2];
    #pragma unroll
    for (int j = 0; j < 2; ++j) {
        float mx = 0.0f;
        for (int dy = -1; dy <= 1; ++dy) {
            int yy = y + dy;
            if (yy < 0 || yy >= H_BEV) continue;
            for (int dx = -1; dx <= 1; ++dx) {
                int xx = x + dx;
                if (xx < 0 || xx >= W_BEV) continue;
                mx = fmaxf(mx, mask[(size_t)j * HW_PIX + (yy << 8) + xx]);
            }
        }
        m[j] = mx;
    }
    out[(size_t)0 * HW_PIX + p] = 1.0f;
    out[(size_t)1 * HW_PIX + p] = m[0];
    out[(size_t)2 * HW_PIX + p] = m[0];
    out[(size_t)3 * HW_PIX + p] = 1.0f;
    out[(size_t)4 * HW_PIX + p] = m[1];
}

extern "C" void kernel_launch(void* const* d_in, const int* in_sizes, int n_in,
                              void* d_out, int out_size, void* d_ws, size_t ws_size,
                              hipStream_t stream) {
    const float* hist  = (const float*)d_in[0];
    const float* mlp_w = (const float*)d_in[1];
    const float* mlp_b = (const float*)d_in[2];
    double* part = (double*)d_ws;                     // 16*5*65536 doubles = 41.9 MB
    float*  mask = (float*)(part + (size_t)16 * 5 * HW_PIX);
    float*  out  = (float*)d_out;

    dim3 g1(HW_PIX / (NPAIR * 512), F_FRAMES * CSPLIT);  // 32 x 16 = 512 blocks
    dot_kernel<<<g1, 256, 0, stream>>>(hist, mlp_w, part);
    mask_kernel<<<HW_PIX / 256, 256, 0, stream>>>(part, mlp_b, mask);
    pool_kernel<<<HW_PIX / 256, 256, 0, stream>>>(mask, out);
}

// Round 3
// 818.982 us; speedup vs baseline: 1.0760x; 1.0760x over previous
//
#include <hip/hip_runtime.h>
#include <math.h>

#define HW_PIX 65536
#define H_BEV 256
#define W_BEV 256
#define C_FEAT 128
#define F_FRAMES 4
#define N_AGENTS 5
#define CSPLIT 4
#define CCHUNK (C_FEAT / CSPLIT)   // 32 channels per block

typedef float vf4 __attribute__((ext_vector_type(4)));

struct d4 { double x, y, z, w; };

__device__ __forceinline__ vf4 ntload(const float* p) {
    return __builtin_nontemporal_load((const vf4*)p);
}

__device__ __forceinline__ void fma4(d4& a, const vf4 u, const vf4 v) {
    a.x += (double)u.x * (double)v.x;
    a.y += (double)u.y * (double)v.y;
    a.z += (double)u.z * (double)v.z;
    a.w += (double)u.w * (double)v.w;
}
__device__ __forceinline__ void fma4s(d4& a, const double w, const vf4 v) {
    a.x += w * (double)v.x;
    a.y += w * (double)v.y;
    a.z += w * (double)v.z;
    a.w += w * (double)v.w;
}

// softmax(0.5^i, i=0..3) in double
__device__ __forceinline__ double hist_weight(int i) {
    const double e0 = exp(1.0), e1 = exp(0.5), e2 = exp(0.25), e3 = exp(0.125);
    const double s = e0 + e1 + e2 + e3;
    double v = (i == 0) ? e0 : (i == 1) ? e1 : (i == 2) ? e2 : e3;
    return v / s;
}

// Kernel 1: uniform-work dot kernel. Block = (frame, channel-quarter);
// each thread owns 4 consecutive pixels (float4 = 16 B/lane, 1 KB per
// wave-instruction) and accumulates the 5 dot partials d1=e.n1, d2=e.n2,
// q1=w.n1, q2=w.n2, q4=w.n4 over 32 channels in f64.
//
// Round-3 change: ALL hist loads are NON-TEMPORAL. The 537 MB input stream
// is read exactly once per iteration, and every stream sits at power-of-two
// strides (256 KB channel, 32 MB agent) that alias to the same L2 set group
// (set-index bits [7:17] unchanged) -- pixel-dimension remapping cannot fix
// that (rounds 0-2 proved insensitivity). 'nt' loads stream past the L2 MSHR
// per-set queue. Numerics: load path unchanged -> part is bit-identical.
// Partials layout: part[fs=frame*4+split][dot(5)][HW_PIX] as double.
__global__ __launch_bounds__(256) void dot_kernel(
        const float* __restrict__ hist, const float* __restrict__ mlp_w,
        double* __restrict__ part) {
    const int fs = blockIdx.y;            // 0..15
    const int frame = fs >> 2;
    const int split = fs & 3;
    const int p = (blockIdx.x * blockDim.x + threadIdx.x) << 2;
    const int c0 = split * CCHUNK;

    const float* base = hist + (size_t)frame * N_AGENTS * C_FEAT * HW_PIX
                             + (size_t)c0 * HW_PIX + p;
    const float* a0 = base;                                   // ego (agent 0)
    const float* a1 = base + (size_t)1 * C_FEAT * HW_PIX;     // agent 1
    const float* a2 = base + (size_t)2 * C_FEAT * HW_PIX;     // agent 2
    const float* a4 = base + (size_t)4 * C_FEAT * HW_PIX;     // agent 4

    d4 d1 = {0, 0, 0, 0}, d2 = {0, 0, 0, 0};
    d4 q1 = {0, 0, 0, 0}, q2 = {0, 0, 0, 0}, q4 = {0, 0, 0, 0};

    #pragma unroll 4
    for (int c = 0; c < CCHUNK; ++c) {
        const vf4 e  = ntload(a0 + (size_t)c * HW_PIX);
        const vf4 n1 = ntload(a1 + (size_t)c * HW_PIX);
        const vf4 n2 = ntload(a2 + (size_t)c * HW_PIX);
        const vf4 n4 = ntload(a4 + (size_t)c * HW_PIX);
        const double wc = (double)mlp_w[c0 + c];   // uniform -> scalar
        fma4(d1, e, n1);
        fma4(d2, e, n2);
        fma4s(q1, wc, n1);
        fma4s(q2, wc, n2);
        fma4s(q4, wc, n4);
    }

    double* pb = part + ((size_t)fs * 5) * HW_PIX + p;
    *(double2*)(pb + 0 * HW_PIX)     = make_double2(d1.x, d1.y);
    *(double2*)(pb + 0 * HW_PIX + 2) = make_double2(d1.z, d1.w);
    *(double2*)(pb + 1 * HW_PIX)     = make_double2(d2.x, d2.y);
    *(double2*)(pb + 1 * HW_PIX + 2) = make_double2(d2.z, d2.w);
    *(double2*)(pb + 2 * HW_PIX)     = make_double2(q1.x, q1.y);
    *(double2*)(pb + 2 * HW_PIX + 2) = make_double2(q1.z, q1.w);
    *(double2*)(pb + 3 * HW_PIX)     = make_double2(q2.x, q2.y);
    *(double2*)(pb + 3 * HW_PIX + 2) = make_double2(q2.z, q2.w);
    *(double2*)(pb + 4 * HW_PIX)     = make_double2(q4.x, q4.y);
    *(double2*)(pb + 4 * HW_PIX + 2) = make_double2(q4.z, q4.w);
}

// Kernel 2: per pixel, reduce the 4 channel-splits per frame, softmax over
// {d1,d2} -> ctx.w, sigmoid, history-weight sum over frames, threshold.
__global__ __launch_bounds__(256) void mask_kernel(
        const double* __restrict__ part, const float* __restrict__ mlp_b,
        float* __restrict__ mask) {
    const int p = blockIdx.x * blockDim.x + threadIdx.x;
    if (p >= HW_PIX) return;
    const double bias = (double)mlp_b[0];
    const double scale = 0.08838834764831844506;  // 1/sqrt(128)
    double acc0 = 0.0, acc1 = 0.0;
    #pragma unroll
    for (int f = 0; f < F_FRAMES; ++f) {
        double d1 = 0, d2 = 0, q1 = 0, q2 = 0, q4 = 0;
        #pragma unroll
        for (int s = 0; s < CSPLIT; ++s) {
            const double* pp = part + ((size_t)(f * CSPLIT + s) * 5) * HW_PIX + p;
            d1 += pp[0 * HW_PIX];
            d2 += pp[1 * HW_PIX];
            q1 += pp[2 * HW_PIX];
            q2 += pp[3 * HW_PIX];
            q4 += pp[4 * HW_PIX];
        }
        double x1 = d1 * scale, x2 = d2 * scale;
        double m = fmax(x1, x2);
        double e1 = exp(x1 - m), e2 = exp(x2 - m);
        double ctxw = (e1 * q1 + e2 * q2) / (e1 + e2) + bias;
        double s0 = 1.0 / (1.0 + exp(-ctxw));        // chunk0 neighbor score
        double s1 = 1.0 / (1.0 + exp(-(q4 + bias))); // chunk1 neighbor score
        double hwf = hist_weight(f);
        acc0 += hwf * s0;
        acc1 += hwf * s1;
    }
    mask[p]          = (acc0 > 0.5) ? 1.0f : 0.0f;
    mask[HW_PIX + p] = (acc1 > 0.5) ? 1.0f : 0.0f;
}

// Kernel 3: 3x3 clamped max-pool on {0,1} masks; egos (agents 0,3) are 1.0.
__global__ __launch_bounds__(256) void pool_kernel(
        const float* __restrict__ mask, float* __restrict__ out) {
    const int p = blockIdx.x * blockDim.x + threadIdx.x;
    if (p >= HW_PIX) return;
    const int y = p >> 8, x = p & 255;
    float m[2];
    #pragma unroll
    for (int j = 0; j < 2; ++j) {
        float mx = 0.0f;
        for (int dy = -1; dy <= 1; ++dy) {
            int yy = y + dy;
            if (yy < 0 || yy >= H_BEV) continue;
            for (int dx = -1; dx <= 1; ++dx) {
                int xx = x + dx;
                if (xx < 0 || xx >= W_BEV) continue;
                mx = fmaxf(mx, mask[(size_t)j * HW_PIX + (yy << 8) + xx]);
            }
        }
        m[j] = mx;
    }
    out[(size_t)0 * HW_PIX + p] = 1.0f;
    out[(size_t)1 * HW_PIX + p] = m[0];
    out[(size_t)2 * HW_PIX + p] = m[0];
    out[(size_t)3 * HW_PIX + p] = 1.0f;
    out[(size_t)4 * HW_PIX + p] = m[1];
}

extern "C" void kernel_launch(void* const* d_in, const int* in_sizes, int n_in,
                              void* d_out, int out_size, void* d_ws, size_t ws_size,
                              hipStream_t stream) {
    const float* hist  = (const float*)d_in[0];
    const float* mlp_w = (const float*)d_in[1];
    const float* mlp_b = (const float*)d_in[2];
    double* part = (double*)d_ws;                     // 16*5*65536 doubles = 41.9 MB
    float*  mask = (float*)(part + (size_t)16 * 5 * HW_PIX);
    float*  out  = (float*)d_out;

    dim3 g1(HW_PIX / (4 * 256), F_FRAMES * CSPLIT);   // 64 x 16 = 1024 blocks
    dot_kernel<<<g1, 256, 0, stream>>>(hist, mlp_w, part);
    mask_kernel<<<HW_PIX / 256, 256, 0, stream>>>(part, mlp_b, mask);
    pool_kernel<<<HW_PIX / 256, 256, 0, stream>>>(mask, out);
}